// Round 7
// baseline (99.196 us; speedup 1.0000x reference)
//
#include <hip/hip_runtime.h>
#include <math.h>

#define BATCH 4096
#define DIM 128
#define LU 10
#define LI 20

typedef float  f32x4  __attribute__((ext_vector_type(4)));
typedef short  s16x8  __attribute__((ext_vector_type(8)));

// round-to-nearest-even fp32 -> bf16
__device__ __forceinline__ short f2bf(float x) {
    unsigned u = __float_as_uint(x);
    u += 0x7FFFu + ((u >> 16) & 1u);
    return (short)(u >> 16);
}

// ---------------------------------------------------------------------------
// K_prep: transpose+convert weights to bf16, convert ef_item to bf16.
// ---------------------------------------------------------------------------
__global__ __launch_bounds__(256) void k_prep(
    const float* __restrict__ enc_W, const float* __restrict__ dec_W,
    const float* __restrict__ fc11_W, const float* __restrict__ fc12_W,
    const float* __restrict__ W_pop, const float* __restrict__ W_int,
    const float* __restrict__ ef_item,
    short* __restrict__ encWT, short* __restrict__ decWT,
    short* __restrict__ fc11WT, short* __restrict__ fc12WT,
    short* __restrict__ wpopT, short* __restrict__ wintT,
    short* __restrict__ ef16)
{
    __shared__ float tile[32][33];
    const int b = blockIdx.x;
    const int t = threadIdx.x;

    if (b < 704) {
        const float* src; short* dst; int r0, c0, src_ld, dst_ld;
        if (b < 320) {
            int tk = b % 80, tj = b / 80;
            src = enc_W; dst = encWT; r0 = tk * 32; c0 = tj * 32; src_ld = 128; dst_ld = 2560;
        } else if (b < 640) {
            int tb = b - 320; int tc = tb % 80, td = tb / 80;
            src = dec_W; dst = decWT; r0 = td * 32; c0 = tc * 32; src_ld = 2560; dst_ld = 128;
        } else if (b < 656) {
            int tb = b - 640; int tk = tb % 4, tj = tb / 4;
            src = fc11_W; dst = fc11WT; r0 = tk * 32; c0 = tj * 32; src_ld = 128; dst_ld = 128;
        } else if (b < 672) {
            int tb = b - 656; int tk = tb % 4, tj = tb / 4;
            src = fc12_W; dst = fc12WT; r0 = tk * 32; c0 = tj * 32; src_ld = 128; dst_ld = 128;
        } else if (b < 688) {
            int tb = b - 672; int tk = tb % 4, tj = tb / 4;
            src = W_pop; dst = wpopT; r0 = tk * 32; c0 = tj * 32; src_ld = 128; dst_ld = 128;
        } else {
            int tb = b - 688; int tk = tb % 4, tj = tb / 4;
            src = W_int; dst = wintT; r0 = tk * 32; c0 = tj * 32; src_ld = 128; dst_ld = 128;
        }
        for (int q = 0; q < 4; ++q) {
            int e = t + q * 256;
            int r = e >> 5, c = e & 31;
            tile[r][c] = src[(size_t)(r0 + r) * src_ld + (c0 + c)];
        }
        __syncthreads();
        for (int q = 0; q < 4; ++q) {
            int e = t + q * 256;
            int r = e >> 5, c = e & 31;
            dst[(size_t)(c0 + r) * dst_ld + (r0 + c)] = f2bf(tile[c][r]);
        }
    } else {
        int base = (b - 704) * 1024 + t * 4;
        float4 v = *(const float4*)(ef_item + base);
        short4 o;
        o.x = f2bf(v.x); o.y = f2bf(v.y); o.z = f2bf(v.z); o.w = f2bf(v.w);
        *(short4*)(ef16 + base) = o;
    }
}

// ---------------------------------------------------------------------------
// pool_g<L>: 32-lane half-wave pools one sample/branch (both vectors),
// writes fp32 rows to GLOBAL pooled sections (linear layout).
// ---------------------------------------------------------------------------
template<int L>
__device__ __forceinline__ void pool_g(
    const int* __restrict__ idxp, const int* __restrict__ featp,
    const float* __restrict__ etab, const float* __restrict__ ftab,
    const float* __restrict__ vpop, const float* __restrict__ vint,
    float* __restrict__ poolH, float* __restrict__ poolC,
    int i, int j32)
{
    const int d = j32 * 4;
    const float4 vp = *(const float4*)(vpop + d);
    const float4 vi = *(const float4*)(vint + d);
    const int idx = idxp[i];
    const float4 f0 = *(const float4*)(etab + (size_t)idx * DIM + d);

    float sp[L + 1], si[L + 1];
    int fidx[L];
    sp[0] = f0.x * vp.x + f0.y * vp.y + f0.z * vp.z + f0.w * vp.w;
    si[0] = f0.x * vi.x + f0.y * vi.y + f0.z * vi.z + f0.w * vi.w;
    unsigned mbits = 1u;
#pragma unroll
    for (int l = 0; l < L; ++l) {
        int f = featp[(size_t)i * L + l];
        fidx[l] = f;
        mbits |= (f != 0 ? 2u : 0u) << l;
        float4 fv = *(const float4*)(ftab + (size_t)f * DIM + d);
        sp[l + 1] = fv.x * vp.x + fv.y * vp.y + fv.z * vp.z + fv.w * vp.w;
        si[l + 1] = fv.x * vi.x + fv.y * vi.y + fv.z * vi.z + fv.w * vi.w;
    }

#pragma unroll
    for (int l = 0; l <= L; ++l) {
        float a = sp[l], b = si[l];
        a += __shfl_xor(a, 1, 64);  b += __shfl_xor(b, 1, 64);
        a += __shfl_xor(a, 2, 64);  b += __shfl_xor(b, 2, 64);
        a += __shfl_xor(a, 4, 64);  b += __shfl_xor(b, 4, 64);
        a += __shfl_xor(a, 8, 64);  b += __shfl_xor(b, 8, 64);
        a += __shfl_xor(a, 16, 64); b += __shfl_xor(b, 16, 64);
        sp[l] = a; si[l] = b;
    }

    float mh = sp[0], mc = si[0];
#pragma unroll
    for (int l = 1; l <= L; ++l) {
        bool v = (mbits >> l) & 1u;
        mh = v ? fmaxf(mh, sp[l]) : mh;
        mc = v ? fmaxf(mc, si[l]) : mc;
    }
    float sh = 0.f, sc = 0.f;
#pragma unroll
    for (int l = 0; l <= L; ++l) {
        bool v = (mbits >> l) & 1u;
        float eh = v ? __expf(sp[l] - mh) : 0.f;
        float ec = v ? __expf(si[l] - mc) : 0.f;
        sp[l] = eh; si[l] = ec;
        sh += eh; sc += ec;
    }
    const float rh = 1.f / sh, rc = 1.f / sc;

    float hx = sp[0] * f0.x, hy = sp[0] * f0.y, hz = sp[0] * f0.z, hw = sp[0] * f0.w;
    float cx = si[0] * f0.x, cy = si[0] * f0.y, cz = si[0] * f0.z, cw = si[0] * f0.w;
#pragma unroll
    for (int l = 0; l < L; ++l) {
        float4 fv = *(const float4*)(ftab + (size_t)fidx[l] * DIM + d);
        float wh = sp[l + 1], wc = si[l + 1];
        hx += wh * fv.x; hy += wh * fv.y; hz += wh * fv.z; hw += wh * fv.w;
        cx += wc * fv.x; cy += wc * fv.y; cz += wc * fv.z; cw += wc * fv.w;
    }
    float4 oH; oH.x = hx * rh; oH.y = hy * rh; oH.z = hz * rh; oH.w = hw * rh;
    float4 oC; oC.x = cx * rc; oC.y = cy * rc; oC.z = cz * rc; oC.w = cw * rc;
    *(float4*)(poolH + (size_t)i * DIM + d) = oH;
    *(float4*)(poolC + (size_t)i * DIM + d) = oC;
}

// ---------------------------------------------------------------------------
// kBC: 1024 blocks x 512 threads.
//   blocks [0,256)    : enc -> mu/lv -> z (zbuf) + kld/mmi/zsq partials
//   blocks [256,1024) : pooling, 16 half-wave tasks/block -> global pooled
// ---------------------------------------------------------------------------
__global__ __launch_bounds__(512) void kBC(
    const int* __restrict__ user_idx, const int* __restrict__ user_feat,
    const int* __restrict__ pos_idx,  const int* __restrict__ pos_feat,
    const int* __restrict__ neg_idx,  const int* __restrict__ neg_feat,
    const int* __restrict__ comp_idx,
    const float* __restrict__ emb_user, const float* __restrict__ emb_item,
    const float* __restrict__ ef_user,  const float* __restrict__ ef_item,
    const float* __restrict__ pop_u, const float* __restrict__ int_u,
    const float* __restrict__ pop_i, const float* __restrict__ int_i,
    const float* __restrict__ eps,
    const float* __restrict__ enc_b,
    const float* __restrict__ fc11_b, const float* __restrict__ fc12_b,
    const short* __restrict__ encWT,
    const short* __restrict__ fc11WT, const short* __restrict__ fc12WT,
    const short* __restrict__ ef16,
    float* __restrict__ pooled,
    short* __restrict__ zbuf, float* __restrict__ vae_part)
{
    __shared__ int   featsL[320];
    __shared__ int   spi[16], sci[16];
    __shared__ __align__(16) short hlds[2048];
    __shared__ float xbuf[16][128];
    __shared__ float sdots[4][16][3];
    __shared__ float red[512];

    const int t    = threadIdx.x;
    const int w    = t >> 6;
    const int lane = t & 63;
    const int g    = lane >> 4;
    const int q    = lane & 15;
    const size_t SEC = (size_t)BATCH * DIM;

    if (blockIdx.x >= 256) {
        // ======================= POOL BLOCKS =======================
        const int pb  = blockIdx.x - 256;       // [0,768)
        const int br  = pb >> 8;                // branch 0,1,2
        const int i   = (pb & 255) * 16 + (t >> 5);
        const int j32 = t & 31;
        if (br == 0) {
            pool_g<LU>(user_idx, user_feat, emb_user, ef_user, pop_u, int_u,
                       pooled + 0 * SEC, pooled + 1 * SEC, i, j32);
        } else if (br == 1) {
            pool_g<LI>(pos_idx, pos_feat, emb_item, ef_item, pop_i, int_i,
                       pooled + 2 * SEC, pooled + 3 * SEC, i, j32);
        } else {
            pool_g<LI>(neg_idx, neg_feat, emb_item, ef_item, pop_i, int_i,
                       pooled + 4 * SEC, pooled + 5 * SEC, i, j32);
        }
        return;
    }

    // ======================= ENC/Z BLOCKS =======================
    const int i0   = blockIdx.x * 16;
    const int wcol = w & 3;
    const int wpar = w >> 2;

    if (t < 16)      spi[t] = pos_idx[i0 + t];
    else if (t < 32) sci[t - 16] = comp_idx[i0 + t - 16];
    if (t < 320) featsL[t] = pos_feat[i0 * LI + t];
    __syncthreads();

    const int j0 = wcol * 32 + q;
    const int j1 = j0 + 16;
    const short* bbase0 = encWT + (size_t)j0 * 2560 + g * 8;
    const short* bbase1 = encWT + (size_t)j1 * 2560 + g * 8;

    f32x4 acc0 = {0.f, 0.f, 0.f, 0.f};
    f32x4 acc1 = {0.f, 0.f, 0.f, 0.f};
    for (int l = wpar; l < LI; l += 2) {
        const int f = featsL[q * LI + l];
        const short* arow = ef16 + (size_t)f * DIM + g * 8;
#pragma unroll
        for (int dt = 0; dt < 4; ++dt) {
            const int koff = l * 128 + dt * 32;
            s16x8 a  = *(const s16x8*)(arow + dt * 32);
            s16x8 b0 = *(const s16x8*)(bbase0 + koff);
            s16x8 b1 = *(const s16x8*)(bbase1 + koff);
            acc0 = __builtin_amdgcn_mfma_f32_16x16x32_bf16(a, b0, acc0, 0, 0, 0);
            acc1 = __builtin_amdgcn_mfma_f32_16x16x32_bf16(a, b1, acc1, 0, 0, 0);
        }
    }

    if (wpar == 1) {
#pragma unroll
        for (int r = 0; r < 4; ++r) {
            int s = g * 4 + r;
            xbuf[s][j0] = acc0[r];
            xbuf[s][j1] = acc1[r];
        }
    }
    __syncthreads();
    if (wpar == 0) {
        float eb0 = enc_b[j0], eb1 = enc_b[j1];
#pragma unroll
        for (int r = 0; r < 4; ++r) {
            int s = g * 4 + r;
            float h0 = acc0[r] + xbuf[s][j0] + eb0; h0 = h0 > 0.f ? h0 : 0.f;
            float h1 = acc1[r] + xbuf[s][j1] + eb1; h1 = h1 > 0.f ? h1 : 0.f;
            int swz = (s & 7) << 3;
            hlds[(s * 128 + j0) ^ swz] = f2bf(h0);
            hlds[(s * 128 + j1) ^ swz] = f2bf(h1);
        }
    }
    __syncthreads();

    const short* WT  = (wpar == 0) ? fc11WT : fc12WT;
    const short* fb0 = WT + (size_t)j0 * DIM + g * 8;
    const short* fb1 = WT + (size_t)j1 * DIM + g * 8;
    f32x4 r0v = {0.f,0.f,0.f,0.f}, r1v = {0.f,0.f,0.f,0.f};
#pragma unroll
    for (int kt = 0; kt < 4; ++kt) {
        int sidx = (q * 128 + kt * 32 + g * 8) ^ ((q & 7) << 3);
        s16x8 a  = *(const s16x8*)&hlds[sidx];
        s16x8 w0 = *(const s16x8*)(fb0 + kt * 32);
        s16x8 w1 = *(const s16x8*)(fb1 + kt * 32);
        r0v = __builtin_amdgcn_mfma_f32_16x16x32_bf16(a, w0, r0v, 0, 0, 0);
        r1v = __builtin_amdgcn_mfma_f32_16x16x32_bf16(a, w1, r1v, 0, 0, 0);
    }
    if (wpar == 1) {
        float b12_0 = fc12_b[j0], b12_1 = fc12_b[j1];
#pragma unroll
        for (int r = 0; r < 4; ++r) {
            int s = g * 4 + r;
            xbuf[s][j0] = r0v[r] + b12_0;
            xbuf[s][j1] = r1v[r] + b12_1;
        }
    }
    __syncthreads();

    float kacc = 0.f;
    if (wpar == 0) {
        float b11_0 = fc11_b[j0], b11_1 = fc11_b[j1];
#pragma unroll
        for (int r = 0; r < 4; ++r) {
            const int s = g * 4 + r;
            const int i = i0 + s;
            float m0 = r0v[r] + b11_0, m1 = r1v[r] + b11_1;
            float v0 = xbuf[s][j0],    v1 = xbuf[s][j1];
            float e0 = eps[(size_t)i * DIM + j0];
            float e1 = eps[(size_t)i * DIM + j1];
            float z0 = e0 * expf(0.5f * v0) + m0;
            float z1 = e1 * expf(0.5f * v1) + m1;
            zbuf[(size_t)i * DIM + j0] = f2bf(z0);
            zbuf[(size_t)i * DIM + j1] = f2bf(z1);
            kacc += (1.f + v0 - m0 * m0 - expf(v0)) + (1.f + v1 - m1 * m1 - expf(v1));

            const size_t pb2 = (size_t)spi[s] * DIM;
            const size_t cb2 = (size_t)sci[s] * DIM;
            float pe0 = emb_item[pb2 + j0], pe1 = emb_item[pb2 + j1];
            float ce0 = emb_item[cb2 + j0], ce1 = emb_item[cb2 + j1];
            float zp = z0 * pe0 + z1 * pe1;
            float zc = z0 * ce0 + z1 * ce1;
            float d0 = z0 - pe0, d1 = z1 - pe1;
            float zq = d0 * d0 + d1 * d1;
            for (int mm = 8; mm >= 1; mm >>= 1) {
                zp += __shfl_xor(zp, mm, 64);
                zc += __shfl_xor(zc, mm, 64);
                zq += __shfl_xor(zq, mm, 64);
            }
            if (q == 0) {
                sdots[w][s][0] = zp;
                sdots[w][s][1] = zc;
                sdots[w][s][2] = zq;
            }
        }
    }

    red[t] = -0.5f * kacc;
    __syncthreads();
    if (t < 16) {
        float zp = 0.f, zc = 0.f, zq = 0.f;
        for (int ww = 0; ww < 4; ++ww) {
            zp += sdots[ww][t][0];
            zc += sdots[ww][t][1];
            zq += sdots[ww][t][2];
        }
        float x = zp - zc;
        float ls = (x >= 0.f) ? -log1pf(expf(-x)) : (x - log1pf(expf(x)));
        red[t] += -ls + zq;
    }
    __syncthreads();
    for (int off = 256; off > 0; off >>= 1) {
        if (t < off) red[t] += red[t + off];
        __syncthreads();
    }
    if (t == 0) vae_part[blockIdx.x] = red[0];
}

// ---------------------------------------------------------------------------
// kD: 2304 blocks x 256 threads.
//   blocks [0,256)    : triplet losses via MFMA (reads global pooled)
//   blocks [256,2304) : decoder col-split x8 -> mse partials
// ---------------------------------------------------------------------------
__global__ __launch_bounds__(256) void kD(
    const float* __restrict__ pooled,
    const short* __restrict__ wpopT, const short* __restrict__ wintT,
    const int* __restrict__ pos_feat,
    const float* __restrict__ ef_item, const float* __restrict__ dec_b,
    const short* __restrict__ decWT, const short* __restrict__ zbuf,
    float* __restrict__ out_hot, float* __restrict__ out_cold,
    float* __restrict__ dec_part)
{
    __shared__ int   featsL[320];
    __shared__ float red[256];
    __shared__ float sArr[4][16];

    const int t    = threadIdx.x;
    const int w    = t >> 6;
    const int lane = t & 63;
    const int g    = lane >> 4;
    const int q    = lane & 15;

    if (blockIdx.x < 256) {
        // =================== TRIPLET LOSS BLOCKS ===================
        const int i0 = blockIdx.x * 16;
        const int h     = w >> 1;
        const int other = (w & 1) + 1;
        const float* pu = pooled + (size_t)(0 * 2 + h) * BATCH * DIM;
        const float* po = pooled + (size_t)(other * 2 + h) * BATCH * DIM;
        const short* wT = h ? wintT : wpopT;

        s16x8 afr[4];
#pragma unroll
        for (int kt = 0; kt < 4; ++kt) {
            const size_t off = (size_t)(i0 + q) * DIM + kt * 32 + g * 8;
            f32x4 ua = *(const f32x4*)(pu + off);
            f32x4 ub = *(const f32x4*)(pu + off + 4);
            f32x4 oa = *(const f32x4*)(po + off);
            f32x4 ob = *(const f32x4*)(po + off + 4);
            s16x8 v;
            v[0] = f2bf(ua[0] - oa[0]); v[1] = f2bf(ua[1] - oa[1]);
            v[2] = f2bf(ua[2] - oa[2]); v[3] = f2bf(ua[3] - oa[3]);
            v[4] = f2bf(ub[0] - ob[0]); v[5] = f2bf(ub[1] - ob[1]);
            v[6] = f2bf(ub[2] - ob[2]); v[7] = f2bf(ub[3] - ob[3]);
            afr[kt] = v;
        }

        float sq0 = 0.f, sq1 = 0.f, sq2 = 0.f, sq3 = 0.f;
        for (int fr = 0; fr < 8; ++fr) {
            const short* bb = wT + (size_t)(fr * 16 + q) * DIM + g * 8;
            f32x4 acc = {0.f, 0.f, 0.f, 0.f};
#pragma unroll
            for (int kt = 0; kt < 4; ++kt) {
                s16x8 bfr = *(const s16x8*)(bb + kt * 32);
                acc = __builtin_amdgcn_mfma_f32_16x16x32_bf16(afr[kt], bfr, acc, 0, 0, 0);
            }
            sq0 += acc[0] * acc[0]; sq1 += acc[1] * acc[1];
            sq2 += acc[2] * acc[2]; sq3 += acc[3] * acc[3];
        }
        for (int m = 8; m >= 1; m >>= 1) {
            sq0 += __shfl_xor(sq0, m, 64);
            sq1 += __shfl_xor(sq1, m, 64);
            sq2 += __shfl_xor(sq2, m, 64);
            sq3 += __shfl_xor(sq3, m, 64);
        }
        if (q == 0) {
            sArr[w][g * 4 + 0] = sq0;
            sArr[w][g * 4 + 1] = sq1;
            sArr[w][g * 4 + 2] = sq2;
            sArr[w][g * 4 + 3] = sq3;
        }
        __syncthreads();
        if (t < 16) {
            float v = sArr[0][t] - sArr[1][t] + 1.0f;
            out_hot[i0 + t] = v > 0.f ? v : 0.f;
        } else if (t < 32) {
            int s = t - 16;
            float v = sArr[2][s] - sArr[3][s] + 1.0f;
            out_cold[i0 + s] = v > 0.f ? v : 0.f;
        }
        return;
    }

    // ====================== DECODER BLOCKS ======================
    const int db     = blockIdx.x - 256;    // [0,2048)
    const int cchunk = db >> 8;
    const int sb     = db & 255;
    const int i0     = sb * 16;

    if (t < 256) featsL[t] = pos_feat[i0 * LI + t];
    if (t < 64)  featsL[256 + t] = pos_feat[i0 * LI + 256 + t];
    __syncthreads();

    s16x8 za[4];
#pragma unroll
    for (int kt = 0; kt < 4; ++kt)
        za[kt] = *(const s16x8*)(zbuf + (size_t)(i0 + q) * DIM + kt * 32 + g * 8);

    const int cw = cchunk * 320 + w * 80;

    s16x8 bb[5][4];
    float xs[5][4];
    float bias[5];
#pragma unroll
    for (int fp = 0; fp < 5; ++fp) {
        const int c = cw + fp * 16 + q;
        const short* bp = decWT + (size_t)c * DIM + g * 8;
#pragma unroll
        for (int kt = 0; kt < 4; ++kt)
            bb[fp][kt] = *(const s16x8*)(bp + kt * 32);
        const int l = c >> 7, dcol = c & 127;
#pragma unroll
        for (int r = 0; r < 4; ++r)
            xs[fp][r] = ef_item[(size_t)featsL[(g * 4 + r) * LI + l] * DIM + dcol];
        bias[fp] = dec_b[c];
    }

    float macc = 0.f;
#pragma unroll
    for (int fp = 0; fp < 5; ++fp) {
        f32x4 acc = {0.f, 0.f, 0.f, 0.f};
#pragma unroll
        for (int kt = 0; kt < 4; ++kt)
            acc = __builtin_amdgcn_mfma_f32_16x16x32_bf16(za[kt], bb[fp][kt], acc, 0, 0, 0);
#pragma unroll
        for (int r = 0; r < 4; ++r) {
            float dd = acc[r] + bias[fp] - xs[fp][r];
            macc += dd * dd;
        }
    }

    red[t] = macc;
    __syncthreads();
    for (int off = 128; off > 0; off >>= 1) {
        if (t < off) red[t] += red[t + off];
        __syncthreads();
    }
    if (t == 0) dec_part[db] = red[0];
}

// ---------------------------------------------------------------------------
// kE: final scalar = sum(vae_part) + 0.05 * sum(dec_part).
// ---------------------------------------------------------------------------
__global__ __launch_bounds__(256) void kE(
    const float* __restrict__ vae_part, const float* __restrict__ dec_part,
    float* __restrict__ out_scalar)
{
    __shared__ float red[256];
    const int t = threadIdx.x;
    float b3 = 0.f;
    for (int qq = t; qq < 2048; qq += 256) b3 += dec_part[qq];
    red[t] = vae_part[t] + 0.05f * b3;   // mse / LI  (LI = 20)
    __syncthreads();
    for (int off = 128; off > 0; off >>= 1) {
        if (t < off) red[t] += red[t + off];
        __syncthreads();
    }
    if (t == 0) out_scalar[0] = red[0];
}

// ---------------------------------------------------------------------------
extern "C" void kernel_launch(void* const* d_in, const int* in_sizes, int n_in,
                              void* d_out, int out_size, void* d_ws, size_t ws_size,
                              hipStream_t stream) {
    const int*   user_idx  = (const int*)d_in[0];
    const int*   user_feat = (const int*)d_in[1];
    const int*   pos_idx   = (const int*)d_in[2];
    const int*   pos_feat  = (const int*)d_in[3];
    const int*   neg_idx   = (const int*)d_in[4];
    const int*   neg_feat  = (const int*)d_in[5];
    const int*   comp_idx  = (const int*)d_in[6];
    const float* eps       = (const float*)d_in[7];
    const float* emb_user  = (const float*)d_in[8];
    const float* emb_item  = (const float*)d_in[9];
    const float* ef_user   = (const float*)d_in[10];
    const float* ef_item   = (const float*)d_in[11];
    const float* pop_u     = (const float*)d_in[12];
    const float* int_u     = (const float*)d_in[13];
    const float* pop_i     = (const float*)d_in[14];
    const float* int_i     = (const float*)d_in[15];
    const float* W_pop     = (const float*)d_in[16];
    const float* W_int     = (const float*)d_in[18];
    const float* enc_W     = (const float*)d_in[20];
    const float* enc_b     = (const float*)d_in[21];
    const float* dec_W     = (const float*)d_in[22];
    const float* dec_b     = (const float*)d_in[23];
    const float* fc11_W    = (const float*)d_in[24];
    const float* fc11_b    = (const float*)d_in[25];
    const float* fc12_W    = (const float*)d_in[26];
    const float* fc12_b    = (const float*)d_in[27];

    float* out = (float*)d_out;
    char*  ws  = (char*)d_ws;

    short* encWT    = (short*)(ws);                    //   655,360 B
    short* decWT    = (short*)(ws + 655360);           //   655,360
    short* fc11WT   = (short*)(ws + 1310720);          //    32,768
    short* fc12WT   = (short*)(ws + 1343488);          //    32,768
    short* wpopT    = (short*)(ws + 1376256);          //    32,768
    short* wintT    = (short*)(ws + 1409024);          //    32,768
    short* ef16     = (short*)(ws + 1441792);          // 1,280,000
    short* zbuf     = (short*)(ws + 2721792);          // 1,048,576
    float* pooled   = (float*)(ws + 3770368);          // 12,582,912
    float* vae_part = (float*)(ws + 16353280);         //     1,024
    float* dec_part = (float*)(ws + 16354304);         //     8,192

    k_prep<<<dim3(1329), dim3(256), 0, stream>>>(
        enc_W, dec_W, fc11_W, fc12_W, W_pop, W_int, ef_item,
        encWT, decWT, fc11WT, fc12WT, wpopT, wintT, ef16);

    kBC<<<dim3(1024), dim3(512), 0, stream>>>(
        user_idx, user_feat, pos_idx, pos_feat, neg_idx, neg_feat, comp_idx,
        emb_user, emb_item, ef_user, ef_item,
        pop_u, int_u, pop_i, int_i,
        eps, enc_b, fc11_b, fc12_b,
        encWT, fc11WT, fc12WT, ef16,
        pooled, zbuf, vae_part);

    kD<<<dim3(2304), dim3(256), 0, stream>>>(
        pooled, wpopT, wintT, pos_feat, ef_item, dec_b, decWT, zbuf,
        out, out + BATCH, dec_part);

    kE<<<dim3(1), dim3(256), 0, stream>>>(vae_part, dec_part, out + 2 * BATCH);
}

// Round 8
// 92.697 us; speedup vs baseline: 1.0701x; 1.0701x over previous
//
#include <hip/hip_runtime.h>
#include <math.h>

#define BATCH 4096
#define DIM 128
#define LU 10
#define LI 20

typedef float  f32x4  __attribute__((ext_vector_type(4)));
typedef short  s16x8  __attribute__((ext_vector_type(8)));

// round-to-nearest-even fp32 -> bf16
__device__ __forceinline__ short f2bf(float x) {
    unsigned u = __float_as_uint(x);
    u += 0x7FFFu + ((u >> 16) & 1u);
    return (short)(u >> 16);
}

// ---------------------------------------------------------------------------
// K_prep: transpose+convert weights to bf16, convert ef_item to bf16.
// ---------------------------------------------------------------------------
__global__ __launch_bounds__(256) void k_prep(
    const float* __restrict__ enc_W, const float* __restrict__ dec_W,
    const float* __restrict__ fc11_W, const float* __restrict__ fc12_W,
    const float* __restrict__ W_pop, const float* __restrict__ W_int,
    const float* __restrict__ ef_item,
    short* __restrict__ encWT, short* __restrict__ decWT,
    short* __restrict__ fc11WT, short* __restrict__ fc12WT,
    short* __restrict__ wpopT, short* __restrict__ wintT,
    short* __restrict__ ef16)
{
    __shared__ float tile[32][33];
    const int b = blockIdx.x;
    const int t = threadIdx.x;

    if (b < 704) {
        const float* src; short* dst; int r0, c0, src_ld, dst_ld;
        if (b < 320) {
            int tk = b % 80, tj = b / 80;
            src = enc_W; dst = encWT; r0 = tk * 32; c0 = tj * 32; src_ld = 128; dst_ld = 2560;
        } else if (b < 640) {
            int tb = b - 320; int tc = tb % 80, td = tb / 80;
            src = dec_W; dst = decWT; r0 = td * 32; c0 = tc * 32; src_ld = 2560; dst_ld = 128;
        } else if (b < 656) {
            int tb = b - 640; int tk = tb % 4, tj = tb / 4;
            src = fc11_W; dst = fc11WT; r0 = tk * 32; c0 = tj * 32; src_ld = 128; dst_ld = 128;
        } else if (b < 672) {
            int tb = b - 656; int tk = tb % 4, tj = tb / 4;
            src = fc12_W; dst = fc12WT; r0 = tk * 32; c0 = tj * 32; src_ld = 128; dst_ld = 128;
        } else if (b < 688) {
            int tb = b - 672; int tk = tb % 4, tj = tb / 4;
            src = W_pop; dst = wpopT; r0 = tk * 32; c0 = tj * 32; src_ld = 128; dst_ld = 128;
        } else {
            int tb = b - 688; int tk = tb % 4, tj = tb / 4;
            src = W_int; dst = wintT; r0 = tk * 32; c0 = tj * 32; src_ld = 128; dst_ld = 128;
        }
        for (int q = 0; q < 4; ++q) {
            int e = t + q * 256;
            int r = e >> 5, c = e & 31;
            tile[r][c] = src[(size_t)(r0 + r) * src_ld + (c0 + c)];
        }
        __syncthreads();
        for (int q = 0; q < 4; ++q) {
            int e = t + q * 256;
            int r = e >> 5, c = e & 31;
            dst[(size_t)(c0 + r) * dst_ld + (r0 + c)] = f2bf(tile[c][r]);
        }
    } else {
        int base = (b - 704) * 1024 + t * 4;
        float4 v = *(const float4*)(ef_item + base);
        short4 o;
        o.x = f2bf(v.x); o.y = f2bf(v.y); o.z = f2bf(v.z); o.w = f2bf(v.w);
        *(short4*)(ef16 + base) = o;
    }
}

// ---------------------------------------------------------------------------
// pool_reg<L>: 32-lane half-wave pools one sample/branch, both vectors,
// with ALL rows held in registers (single load per row, no second pass).
// ---------------------------------------------------------------------------
template<int L>
__device__ __forceinline__ void pool_reg(
    const int* __restrict__ idxp, const int* __restrict__ featp,
    const float* __restrict__ etab, const float* __restrict__ ftab,
    const float* __restrict__ vpop, const float* __restrict__ vint,
    float* __restrict__ poolH, float* __restrict__ poolC,
    int i, int j32)
{
    const int d = j32 * 4;
    const float4 vp = *(const float4*)(vpop + d);
    const float4 vi = *(const float4*)(vint + d);

    float4 r[L + 1];
    const int idx = idxp[i];
    r[0] = *(const float4*)(etab + (size_t)idx * DIM + d);
    unsigned mbits = 1u;
#pragma unroll
    for (int l = 0; l < L; ++l) {
        int f = featp[(size_t)i * L + l];
        mbits |= (f != 0 ? 2u : 0u) << l;
        r[l + 1] = *(const float4*)(ftab + (size_t)f * DIM + d);
    }

    float sp[L + 1], si[L + 1];
#pragma unroll
    for (int l = 0; l <= L; ++l) {
        sp[l] = r[l].x * vp.x + r[l].y * vp.y + r[l].z * vp.z + r[l].w * vp.w;
        si[l] = r[l].x * vi.x + r[l].y * vi.y + r[l].z * vi.z + r[l].w * vi.w;
    }

#pragma unroll
    for (int l = 0; l <= L; ++l) {
        float a = sp[l], b = si[l];
        a += __shfl_xor(a, 1, 64);  b += __shfl_xor(b, 1, 64);
        a += __shfl_xor(a, 2, 64);  b += __shfl_xor(b, 2, 64);
        a += __shfl_xor(a, 4, 64);  b += __shfl_xor(b, 4, 64);
        a += __shfl_xor(a, 8, 64);  b += __shfl_xor(b, 8, 64);
        a += __shfl_xor(a, 16, 64); b += __shfl_xor(b, 16, 64);
        sp[l] = a; si[l] = b;
    }

    float mh = sp[0], mc = si[0];
#pragma unroll
    for (int l = 1; l <= L; ++l) {
        bool v = (mbits >> l) & 1u;
        mh = v ? fmaxf(mh, sp[l]) : mh;
        mc = v ? fmaxf(mc, si[l]) : mc;
    }
    float sh = 0.f, sc = 0.f;
#pragma unroll
    for (int l = 0; l <= L; ++l) {
        bool v = (mbits >> l) & 1u;
        float eh = v ? __expf(sp[l] - mh) : 0.f;
        float ec = v ? __expf(si[l] - mc) : 0.f;
        sp[l] = eh; si[l] = ec;
        sh += eh; sc += ec;
    }
    const float rh = 1.f / sh, rc = 1.f / sc;

    float hx = sp[0] * r[0].x, hy = sp[0] * r[0].y, hz = sp[0] * r[0].z, hw = sp[0] * r[0].w;
    float cx = si[0] * r[0].x, cy = si[0] * r[0].y, cz = si[0] * r[0].z, cw = si[0] * r[0].w;
#pragma unroll
    for (int l = 1; l <= L; ++l) {
        float wh = sp[l], wc = si[l];
        hx += wh * r[l].x; hy += wh * r[l].y; hz += wh * r[l].z; hw += wh * r[l].w;
        cx += wc * r[l].x; cy += wc * r[l].y; cz += wc * r[l].z; cw += wc * r[l].w;
    }
    float4 oH; oH.x = hx * rh; oH.y = hy * rh; oH.z = hz * rh; oH.w = hw * rh;
    float4 oC; oC.x = cx * rc; oC.y = cy * rc; oC.z = cz * rc; oC.w = cw * rc;
    *(float4*)(poolH + (size_t)i * DIM + d) = oH;
    *(float4*)(poolC + (size_t)i * DIM + d) = oC;
}

// ---------------------------------------------------------------------------
// K_main: 1024 blocks x 512 threads.
//   blocks [0,256)    : fused VAE (enc -> mu/lv -> z -> dec inline + partials)
//   blocks [256,1024) : pooling (branch-split, 16 half-wave tasks) -> global
// ---------------------------------------------------------------------------
__global__ __launch_bounds__(512) void k_main(
    const int* __restrict__ user_idx, const int* __restrict__ user_feat,
    const int* __restrict__ pos_idx,  const int* __restrict__ pos_feat,
    const int* __restrict__ neg_idx,  const int* __restrict__ neg_feat,
    const int* __restrict__ comp_idx,
    const float* __restrict__ emb_user, const float* __restrict__ emb_item,
    const float* __restrict__ ef_user,  const float* __restrict__ ef_item,
    const float* __restrict__ pop_u, const float* __restrict__ int_u,
    const float* __restrict__ pop_i, const float* __restrict__ int_i,
    const float* __restrict__ eps,
    const float* __restrict__ enc_b, const float* __restrict__ dec_b,
    const float* __restrict__ fc11_b, const float* __restrict__ fc12_b,
    const short* __restrict__ encWT, const short* __restrict__ decWT,
    const short* __restrict__ fc11WT, const short* __restrict__ fc12WT,
    const short* __restrict__ ef16,
    float* __restrict__ pooled, float* __restrict__ vae_part)
{
    __shared__ int   featsL[320];
    __shared__ int   spi[16], sci[16];
    __shared__ __align__(16) short hlds[2048];
    __shared__ float xbuf[16][128];
    __shared__ float sdots[4][16][3];
    __shared__ float red[512];

    const int t    = threadIdx.x;
    const int w    = t >> 6;
    const int lane = t & 63;
    const int g    = lane >> 4;
    const int q    = lane & 15;
    const size_t SEC = (size_t)BATCH * DIM;

    if (blockIdx.x >= 256) {
        // ======================= POOL BLOCKS =======================
        const int pb  = blockIdx.x - 256;       // [0,768)
        const int br  = pb >> 8;                // branch 0,1,2
        const int i   = (pb & 255) * 16 + (t >> 5);
        const int j32 = t & 31;
        if (br == 0) {
            pool_reg<LU>(user_idx, user_feat, emb_user, ef_user, pop_u, int_u,
                         pooled + 0 * SEC, pooled + 1 * SEC, i, j32);
        } else if (br == 1) {
            pool_reg<LI>(pos_idx, pos_feat, emb_item, ef_item, pop_i, int_i,
                         pooled + 2 * SEC, pooled + 3 * SEC, i, j32);
        } else {
            pool_reg<LI>(neg_idx, neg_feat, emb_item, ef_item, pop_i, int_i,
                         pooled + 4 * SEC, pooled + 5 * SEC, i, j32);
        }
        return;
    }

    // ====================== FUSED VAE BLOCKS ======================
    const int i0   = blockIdx.x * 16;
    const int wcol = w & 3;
    const int wpar = w >> 2;

    if (t < 16)      spi[t] = pos_idx[i0 + t];
    else if (t < 32) sci[t - 16] = comp_idx[i0 + t - 16];
    if (t < 320) featsL[t] = pos_feat[i0 * LI + t];
    __syncthreads();

    const int j0 = wcol * 32 + q;
    const int j1 = j0 + 16;
    const short* bbase0 = encWT + (size_t)j0 * 2560 + g * 8;
    const short* bbase1 = encWT + (size_t)j1 * 2560 + g * 8;

    f32x4 acc0 = {0.f, 0.f, 0.f, 0.f};
    f32x4 acc1 = {0.f, 0.f, 0.f, 0.f};
    for (int l = wpar; l < LI; l += 2) {
        const int f = featsL[q * LI + l];
        const short* arow = ef16 + (size_t)f * DIM + g * 8;
#pragma unroll
        for (int dt = 0; dt < 4; ++dt) {
            const int koff = l * 128 + dt * 32;
            s16x8 a  = *(const s16x8*)(arow + dt * 32);
            s16x8 b0 = *(const s16x8*)(bbase0 + koff);
            s16x8 b1 = *(const s16x8*)(bbase1 + koff);
            acc0 = __builtin_amdgcn_mfma_f32_16x16x32_bf16(a, b0, acc0, 0, 0, 0);
            acc1 = __builtin_amdgcn_mfma_f32_16x16x32_bf16(a, b1, acc1, 0, 0, 0);
        }
    }

    if (wpar == 1) {
#pragma unroll
        for (int r = 0; r < 4; ++r) {
            int s = g * 4 + r;
            xbuf[s][j0] = acc0[r];
            xbuf[s][j1] = acc1[r];
        }
    }
    __syncthreads();
    if (wpar == 0) {
        float eb0 = enc_b[j0], eb1 = enc_b[j1];
#pragma unroll
        for (int r = 0; r < 4; ++r) {
            int s = g * 4 + r;
            float h0 = acc0[r] + xbuf[s][j0] + eb0; h0 = h0 > 0.f ? h0 : 0.f;
            float h1 = acc1[r] + xbuf[s][j1] + eb1; h1 = h1 > 0.f ? h1 : 0.f;
            int swz = (s & 7) << 3;
            hlds[(s * 128 + j0) ^ swz] = f2bf(h0);
            hlds[(s * 128 + j1) ^ swz] = f2bf(h1);
        }
    }
    __syncthreads();

    const short* WT  = (wpar == 0) ? fc11WT : fc12WT;
    const short* fb0 = WT + (size_t)j0 * DIM + g * 8;
    const short* fb1 = WT + (size_t)j1 * DIM + g * 8;
    f32x4 r0v = {0.f,0.f,0.f,0.f}, r1v = {0.f,0.f,0.f,0.f};
#pragma unroll
    for (int kt = 0; kt < 4; ++kt) {
        int sidx = (q * 128 + kt * 32 + g * 8) ^ ((q & 7) << 3);
        s16x8 a  = *(const s16x8*)&hlds[sidx];
        s16x8 w0 = *(const s16x8*)(fb0 + kt * 32);
        s16x8 w1 = *(const s16x8*)(fb1 + kt * 32);
        r0v = __builtin_amdgcn_mfma_f32_16x16x32_bf16(a, w0, r0v, 0, 0, 0);
        r1v = __builtin_amdgcn_mfma_f32_16x16x32_bf16(a, w1, r1v, 0, 0, 0);
    }
    if (wpar == 1) {
        float b12_0 = fc12_b[j0], b12_1 = fc12_b[j1];
#pragma unroll
        for (int r = 0; r < 4; ++r) {
            int s = g * 4 + r;
            xbuf[s][j0] = r0v[r] + b12_0;
            xbuf[s][j1] = r1v[r] + b12_1;
        }
    }
    __syncthreads();

    float kacc = 0.f;
    if (wpar == 0) {
        float b11_0 = fc11_b[j0], b11_1 = fc11_b[j1];
#pragma unroll
        for (int r = 0; r < 4; ++r) {
            const int s = g * 4 + r;
            const int i = i0 + s;
            float m0 = r0v[r] + b11_0, m1 = r1v[r] + b11_1;
            float v0 = xbuf[s][j0],    v1 = xbuf[s][j1];
            float e0 = eps[(size_t)i * DIM + j0];
            float e1 = eps[(size_t)i * DIM + j1];
            float z0 = e0 * expf(0.5f * v0) + m0;
            float z1 = e1 * expf(0.5f * v1) + m1;
            int swz = (s & 7) << 3;
            hlds[(s * 128 + j0) ^ swz] = f2bf(z0);
            hlds[(s * 128 + j1) ^ swz] = f2bf(z1);
            kacc += (1.f + v0 - m0 * m0 - expf(v0)) + (1.f + v1 - m1 * m1 - expf(v1));

            const size_t pb2 = (size_t)spi[s] * DIM;
            const size_t cb2 = (size_t)sci[s] * DIM;
            float pe0 = emb_item[pb2 + j0], pe1 = emb_item[pb2 + j1];
            float ce0 = emb_item[cb2 + j0], ce1 = emb_item[cb2 + j1];
            float zp = z0 * pe0 + z1 * pe1;
            float zc = z0 * ce0 + z1 * ce1;
            float d0 = z0 - pe0, d1 = z1 - pe1;
            float zq = d0 * d0 + d1 * d1;
            for (int mm = 8; mm >= 1; mm >>= 1) {
                zp += __shfl_xor(zp, mm, 64);
                zc += __shfl_xor(zc, mm, 64);
                zq += __shfl_xor(zq, mm, 64);
            }
            if (q == 0) {
                sdots[w][s][0] = zp;
                sdots[w][s][1] = zc;
                sdots[w][s][2] = zq;
            }
        }
    }
    __syncthreads();

    // decoder + mse (all 8 waves): wave w handles cols [w*320, w*320+320)
    s16x8 za[4];
#pragma unroll
    for (int kt = 0; kt < 4; ++kt)
        za[kt] = *(const s16x8*)&hlds[(q * 128 + kt * 32 + g * 8) ^ ((q & 7) << 3)];

    const int cw = w * 320;
    float macc = 0.f;
    for (int fp = 0; fp < 10; ++fp) {
        const int c0 = cw + fp * 32 + q;
        const int c1 = c0 + 16;
        const short* bp0 = decWT + (size_t)c0 * DIM + g * 8;
        const short* bp1 = decWT + (size_t)c1 * DIM + g * 8;
        s16x8 b0[4], b1[4];
#pragma unroll
        for (int kt = 0; kt < 4; ++kt) {
            b0[kt] = *(const s16x8*)(bp0 + kt * 32);
            b1[kt] = *(const s16x8*)(bp1 + kt * 32);
        }
        const int l0 = c0 >> 7, d0 = c0 & 127;
        const int l1 = c1 >> 7, d1 = c1 & 127;
        float x0[4], x1[4];
#pragma unroll
        for (int r = 0; r < 4; ++r) {
            x0[r] = ef_item[(size_t)featsL[(g * 4 + r) * LI + l0] * DIM + d0];
            x1[r] = ef_item[(size_t)featsL[(g * 4 + r) * LI + l1] * DIM + d1];
        }
        const float bias0 = dec_b[c0], bias1 = dec_b[c1];
        f32x4 a0 = {0.f,0.f,0.f,0.f}, a1 = {0.f,0.f,0.f,0.f};
#pragma unroll
        for (int kt = 0; kt < 4; ++kt) {
            a0 = __builtin_amdgcn_mfma_f32_16x16x32_bf16(za[kt], b0[kt], a0, 0, 0, 0);
            a1 = __builtin_amdgcn_mfma_f32_16x16x32_bf16(za[kt], b1[kt], a1, 0, 0, 0);
        }
#pragma unroll
        for (int r = 0; r < 4; ++r) {
            float dd0 = a0[r] + bias0 - x0[r];
            float dd1 = a1[r] + bias1 - x1[r];
            macc += dd0 * dd0 + dd1 * dd1;
        }
    }

    red[t] = 0.05f * macc + ((wpar == 0) ? -0.5f * kacc : 0.f);  // mse/LI
    __syncthreads();
    if (t < 16) {
        float zp = 0.f, zc = 0.f, zq = 0.f;
        for (int ww = 0; ww < 4; ++ww) {
            zp += sdots[ww][t][0];
            zc += sdots[ww][t][1];
            zq += sdots[ww][t][2];
        }
        float x = zp - zc;
        float ls = (x >= 0.f) ? -log1pf(expf(-x)) : (x - log1pf(expf(x)));
        red[t] += -ls + zq;
    }
    __syncthreads();
    for (int off = 256; off > 0; off >>= 1) {
        if (t < off) red[t] += red[t + off];
        __syncthreads();
    }
    if (t == 0) vae_part[blockIdx.x] = red[0];
}

// ---------------------------------------------------------------------------
// K_loss: 256 blocks x 256 threads — triplet losses via MFMA; block 0 also
// reduces vae_part -> item_vae_loss scalar.
// ---------------------------------------------------------------------------
__global__ __launch_bounds__(256) void k_loss(
    const float* __restrict__ pooled,
    const short* __restrict__ wpopT, const short* __restrict__ wintT,
    const float* __restrict__ vae_part,
    float* __restrict__ out_hot, float* __restrict__ out_cold,
    float* __restrict__ out_scalar)
{
    __shared__ float sArr[4][16];
    __shared__ float red[256];

    const int t    = threadIdx.x;
    const int w    = t >> 6;
    const int lane = t & 63;
    const int g    = lane >> 4;
    const int q    = lane & 15;
    const int i0   = blockIdx.x * 16;

    const int h     = w >> 1;
    const int other = (w & 1) + 1;
    const float* pu = pooled + (size_t)(0 * 2 + h) * BATCH * DIM;
    const float* po = pooled + (size_t)(other * 2 + h) * BATCH * DIM;
    const short* wT = h ? wintT : wpopT;

    s16x8 afr[4];
#pragma unroll
    for (int kt = 0; kt < 4; ++kt) {
        const size_t off = (size_t)(i0 + q) * DIM + kt * 32 + g * 8;
        f32x4 ua = *(const f32x4*)(pu + off);
        f32x4 ub = *(const f32x4*)(pu + off + 4);
        f32x4 oa = *(const f32x4*)(po + off);
        f32x4 ob = *(const f32x4*)(po + off + 4);
        s16x8 v;
        v[0] = f2bf(ua[0] - oa[0]); v[1] = f2bf(ua[1] - oa[1]);
        v[2] = f2bf(ua[2] - oa[2]); v[3] = f2bf(ua[3] - oa[3]);
        v[4] = f2bf(ub[0] - ob[0]); v[5] = f2bf(ub[1] - ob[1]);
        v[6] = f2bf(ub[2] - ob[2]); v[7] = f2bf(ub[3] - ob[3]);
        afr[kt] = v;
    }

    float sq0 = 0.f, sq1 = 0.f, sq2 = 0.f, sq3 = 0.f;
    for (int fr = 0; fr < 8; ++fr) {
        const short* bb = wT + (size_t)(fr * 16 + q) * DIM + g * 8;
        f32x4 acc = {0.f, 0.f, 0.f, 0.f};
#pragma unroll
        for (int kt = 0; kt < 4; ++kt) {
            s16x8 bfr = *(const s16x8*)(bb + kt * 32);
            acc = __builtin_amdgcn_mfma_f32_16x16x32_bf16(afr[kt], bfr, acc, 0, 0, 0);
        }
        sq0 += acc[0] * acc[0]; sq1 += acc[1] * acc[1];
        sq2 += acc[2] * acc[2]; sq3 += acc[3] * acc[3];
    }
    for (int m = 8; m >= 1; m >>= 1) {
        sq0 += __shfl_xor(sq0, m, 64);
        sq1 += __shfl_xor(sq1, m, 64);
        sq2 += __shfl_xor(sq2, m, 64);
        sq3 += __shfl_xor(sq3, m, 64);
    }
    if (q == 0) {
        sArr[w][g * 4 + 0] = sq0;
        sArr[w][g * 4 + 1] = sq1;
        sArr[w][g * 4 + 2] = sq2;
        sArr[w][g * 4 + 3] = sq3;
    }
    __syncthreads();
    if (t < 16) {
        float v = sArr[0][t] - sArr[1][t] + 1.0f;
        out_hot[i0 + t] = v > 0.f ? v : 0.f;
    } else if (t < 32) {
        int s = t - 16;
        float v = sArr[2][s] - sArr[3][s] + 1.0f;
        out_cold[i0 + s] = v > 0.f ? v : 0.f;
    }

    if (blockIdx.x == 0) {
        red[t] = vae_part[t];
        __syncthreads();
        for (int off = 128; off > 0; off >>= 1) {
            if (t < off) red[t] += red[t + off];
            __syncthreads();
        }
        if (t == 0) out_scalar[0] = red[0];
    }
}

// ---------------------------------------------------------------------------
extern "C" void kernel_launch(void* const* d_in, const int* in_sizes, int n_in,
                              void* d_out, int out_size, void* d_ws, size_t ws_size,
                              hipStream_t stream) {
    const int*   user_idx  = (const int*)d_in[0];
    const int*   user_feat = (const int*)d_in[1];
    const int*   pos_idx   = (const int*)d_in[2];
    const int*   pos_feat  = (const int*)d_in[3];
    const int*   neg_idx   = (const int*)d_in[4];
    const int*   neg_feat  = (const int*)d_in[5];
    const int*   comp_idx  = (const int*)d_in[6];
    const float* eps       = (const float*)d_in[7];
    const float* emb_user  = (const float*)d_in[8];
    const float* emb_item  = (const float*)d_in[9];
    const float* ef_user   = (const float*)d_in[10];
    const float* ef_item   = (const float*)d_in[11];
    const float* pop_u     = (const float*)d_in[12];
    const float* int_u     = (const float*)d_in[13];
    const float* pop_i     = (const float*)d_in[14];
    const float* int_i     = (const float*)d_in[15];
    const float* W_pop     = (const float*)d_in[16];
    const float* W_int     = (const float*)d_in[18];
    const float* enc_W     = (const float*)d_in[20];
    const float* enc_b     = (const float*)d_in[21];
    const float* dec_W     = (const float*)d_in[22];
    const float* dec_b     = (const float*)d_in[23];
    const float* fc11_W    = (const float*)d_in[24];
    const float* fc11_b    = (const float*)d_in[25];
    const float* fc12_W    = (const float*)d_in[26];
    const float* fc12_b    = (const float*)d_in[27];

    float* out = (float*)d_out;
    char*  ws  = (char*)d_ws;

    short* encWT    = (short*)(ws);                    //   655,360 B
    short* decWT    = (short*)(ws + 655360);           //   655,360
    short* fc11WT   = (short*)(ws + 1310720);          //    32,768
    short* fc12WT   = (short*)(ws + 1343488);          //    32,768
    short* wpopT    = (short*)(ws + 1376256);          //    32,768
    short* wintT    = (short*)(ws + 1409024);          //    32,768
    short* ef16     = (short*)(ws + 1441792);          // 1,280,000
    float* pooled   = (float*)(ws + 2721792);          // 12,582,912
    float* vae_part = (float*)(ws + 15304704);         //     1,024

    k_prep<<<dim3(1329), dim3(256), 0, stream>>>(
        enc_W, dec_W, fc11_W, fc12_W, W_pop, W_int, ef_item,
        encWT, decWT, fc11WT, fc12WT, wpopT, wintT, ef16);

    k_main<<<dim3(1024), dim3(512), 0, stream>>>(
        user_idx, user_feat, pos_idx, pos_feat, neg_idx, neg_feat, comp_idx,
        emb_user, emb_item, ef_user, ef_item,
        pop_u, int_u, pop_i, int_i,
        eps, enc_b, dec_b, fc11_b, fc12_b,
        encWT, decWT, fc11WT, fc12WT, ef16,
        pooled, vae_part);

    k_loss<<<dim3(256), dim3(256), 0, stream>>>(
        pooled, wpopT, wintT, vae_part,
        out, out + BATCH, out + 2 * BATCH);
}

// Round 9
// 91.046 us; speedup vs baseline: 1.0895x; 1.0181x over previous
//
#include <hip/hip_runtime.h>
#include <math.h>

#define BATCH 4096
#define DIM 128
#define LU 10
#define LI 20

typedef float  f32x4  __attribute__((ext_vector_type(4)));
typedef short  s16x8  __attribute__((ext_vector_type(8)));

// round-to-nearest-even fp32 -> bf16
__device__ __forceinline__ short f2bf(float x) {
    unsigned u = __float_as_uint(x);
    u += 0x7FFFu + ((u >> 16) & 1u);
    return (short)(u >> 16);
}
__device__ __forceinline__ float bf2f(unsigned short u) {
    return __uint_as_float(((unsigned)u) << 16);
}

// ---------------------------------------------------------------------------
// K_prep: transpose+convert weights to bf16; ef_item + ef_user to bf16.
//   [0,704)      weight transposes (as before)
//   [704,1329)   ef16  (item features, 5000*128)
//   [1329,1579)  efU16 (user features, 2000*128)
// ---------------------------------------------------------------------------
__global__ __launch_bounds__(256) void k_prep(
    const float* __restrict__ enc_W, const float* __restrict__ dec_W,
    const float* __restrict__ fc11_W, const float* __restrict__ fc12_W,
    const float* __restrict__ W_pop, const float* __restrict__ W_int,
    const float* __restrict__ ef_item, const float* __restrict__ ef_user,
    short* __restrict__ encWT, short* __restrict__ decWT,
    short* __restrict__ fc11WT, short* __restrict__ fc12WT,
    short* __restrict__ wpopT, short* __restrict__ wintT,
    short* __restrict__ ef16, short* __restrict__ efU16)
{
    __shared__ float tile[32][33];
    const int b = blockIdx.x;
    const int t = threadIdx.x;

    if (b < 704) {
        const float* src; short* dst; int r0, c0, src_ld, dst_ld;
        if (b < 320) {
            int tk = b % 80, tj = b / 80;
            src = enc_W; dst = encWT; r0 = tk * 32; c0 = tj * 32; src_ld = 128; dst_ld = 2560;
        } else if (b < 640) {
            int tb = b - 320; int tc = tb % 80, td = tb / 80;
            src = dec_W; dst = decWT; r0 = td * 32; c0 = tc * 32; src_ld = 2560; dst_ld = 128;
        } else if (b < 656) {
            int tb = b - 640; int tk = tb % 4, tj = tb / 4;
            src = fc11_W; dst = fc11WT; r0 = tk * 32; c0 = tj * 32; src_ld = 128; dst_ld = 128;
        } else if (b < 672) {
            int tb = b - 656; int tk = tb % 4, tj = tb / 4;
            src = fc12_W; dst = fc12WT; r0 = tk * 32; c0 = tj * 32; src_ld = 128; dst_ld = 128;
        } else if (b < 688) {
            int tb = b - 672; int tk = tb % 4, tj = tb / 4;
            src = W_pop; dst = wpopT; r0 = tk * 32; c0 = tj * 32; src_ld = 128; dst_ld = 128;
        } else {
            int tb = b - 688; int tk = tb % 4, tj = tb / 4;
            src = W_int; dst = wintT; r0 = tk * 32; c0 = tj * 32; src_ld = 128; dst_ld = 128;
        }
        for (int q = 0; q < 4; ++q) {
            int e = t + q * 256;
            int r = e >> 5, c = e & 31;
            tile[r][c] = src[(size_t)(r0 + r) * src_ld + (c0 + c)];
        }
        __syncthreads();
        for (int q = 0; q < 4; ++q) {
            int e = t + q * 256;
            int r = e >> 5, c = e & 31;
            dst[(size_t)(c0 + r) * dst_ld + (r0 + c)] = f2bf(tile[c][r]);
        }
    } else if (b < 1329) {
        int base = (b - 704) * 1024 + t * 4;
        float4 v = *(const float4*)(ef_item + base);
        short4 o;
        o.x = f2bf(v.x); o.y = f2bf(v.y); o.z = f2bf(v.z); o.w = f2bf(v.w);
        *(short4*)(ef16 + base) = o;
    } else {
        int base = (b - 1329) * 1024 + t * 4;
        float4 v = *(const float4*)(ef_user + base);
        short4 o;
        o.x = f2bf(v.x); o.y = f2bf(v.y); o.z = f2bf(v.z); o.w = f2bf(v.w);
        *(short4*)(efU16 + base) = o;
    }
}

// ---------------------------------------------------------------------------
// pool_online<L>: 32-lane half-wave pools one (sample, branch), both vectors,
// ONLINE softmax — single pass over rows, no row storage (low VGPR).
// Feature rows read as bf16 (halves cache-line traffic); emb row fp32.
// ---------------------------------------------------------------------------
template<int L>
__device__ __forceinline__ void pool_online(
    const int* __restrict__ idxp, const int* __restrict__ featp,
    const float* __restrict__ etab, const unsigned short* __restrict__ ftab16,
    const float* __restrict__ vpop, const float* __restrict__ vint,
    float* __restrict__ poolH, float* __restrict__ poolC,
    int i, int j32)
{
    const int d = j32 * 4;
    const float4 vp = *(const float4*)(vpop + d);
    const float4 vi = *(const float4*)(vint + d);

    // preload all feature indices (independent loads, issue early)
    int fidx[L];
#pragma unroll
    for (int l = 0; l < L; ++l) fidx[l] = featp[(size_t)i * L + l];

    const int idx = idxp[i];
    const float4 e0 = *(const float4*)(etab + (size_t)idx * DIM + d);

    // row 0 scores (always valid)
    float sH = e0.x * vp.x + e0.y * vp.y + e0.z * vp.z + e0.w * vp.w;
    float sC = e0.x * vi.x + e0.y * vi.y + e0.z * vi.z + e0.w * vi.w;
    sH += __shfl_xor(sH, 1, 64);  sC += __shfl_xor(sC, 1, 64);
    sH += __shfl_xor(sH, 2, 64);  sC += __shfl_xor(sC, 2, 64);
    sH += __shfl_xor(sH, 4, 64);  sC += __shfl_xor(sC, 4, 64);
    sH += __shfl_xor(sH, 8, 64);  sC += __shfl_xor(sC, 8, 64);
    sH += __shfl_xor(sH, 16, 64); sC += __shfl_xor(sC, 16, 64);

    float mH = sH, mC = sC;
    float sumH = 1.f, sumC = 1.f;
    float aHx = e0.x, aHy = e0.y, aHz = e0.z, aHw = e0.w;
    float aCx = e0.x, aCy = e0.y, aCz = e0.z, aCw = e0.w;

#pragma unroll
    for (int l = 0; l < L; ++l) {
        const int f = fidx[l];
        const ushort4 u = *(const ushort4*)(ftab16 + (size_t)f * DIM + d);
        const float rx = bf2f(u.x), ry = bf2f(u.y), rz = bf2f(u.z), rw = bf2f(u.w);

        float pH = rx * vp.x + ry * vp.y + rz * vp.z + rw * vp.w;
        float pC = rx * vi.x + ry * vi.y + rz * vi.z + rw * vi.w;
        pH += __shfl_xor(pH, 1, 64);  pC += __shfl_xor(pC, 1, 64);
        pH += __shfl_xor(pH, 2, 64);  pC += __shfl_xor(pC, 2, 64);
        pH += __shfl_xor(pH, 4, 64);  pC += __shfl_xor(pC, 4, 64);
        pH += __shfl_xor(pH, 8, 64);  pC += __shfl_xor(pC, 8, 64);
        pH += __shfl_xor(pH, 16, 64); pC += __shfl_xor(pC, 16, 64);

        const bool v = (f != 0);
        const float mH2 = v ? fmaxf(mH, pH) : mH;
        const float mC2 = v ? fmaxf(mC, pC) : mC;
        const float sclH = __expf(mH - mH2);       // ==1 when invalid
        const float sclC = __expf(mC - mC2);
        const float wH = v ? __expf(pH - mH2) : 0.f;
        const float wC = v ? __expf(pC - mC2) : 0.f;
        sumH = sumH * sclH + wH;
        sumC = sumC * sclC + wC;
        aHx = aHx * sclH + wH * rx;  aHy = aHy * sclH + wH * ry;
        aHz = aHz * sclH + wH * rz;  aHw = aHw * sclH + wH * rw;
        aCx = aCx * sclC + wC * rx;  aCy = aCy * sclC + wC * ry;
        aCz = aCz * sclC + wC * rz;  aCw = aCw * sclC + wC * rw;
        mH = mH2; mC = mC2;
    }

    const float rH = 1.f / sumH, rC = 1.f / sumC;
    float4 oH; oH.x = aHx * rH; oH.y = aHy * rH; oH.z = aHz * rH; oH.w = aHw * rH;
    float4 oC; oC.x = aCx * rC; oC.y = aCy * rC; oC.z = aCz * rC; oC.w = aCw * rC;
    *(float4*)(poolH + (size_t)i * DIM + d) = oH;
    *(float4*)(poolC + (size_t)i * DIM + d) = oC;
}

// ---------------------------------------------------------------------------
// k_AB: 1792 blocks x 256 threads.
//   blocks [0,1536)    : pooling (512 blocks/branch, 8 half-wave tasks each)
//   blocks [1536,1792) : enc -> mu/lv -> z (zbuf) + kld/mmi/zsq partials
// ---------------------------------------------------------------------------
__global__ __launch_bounds__(256) void k_AB(
    const int* __restrict__ user_idx, const int* __restrict__ user_feat,
    const int* __restrict__ pos_idx,  const int* __restrict__ pos_feat,
    const int* __restrict__ neg_idx,  const int* __restrict__ neg_feat,
    const int* __restrict__ comp_idx,
    const float* __restrict__ emb_user, const float* __restrict__ emb_item,
    const float* __restrict__ pop_u, const float* __restrict__ int_u,
    const float* __restrict__ pop_i, const float* __restrict__ int_i,
    const float* __restrict__ eps,
    const float* __restrict__ enc_b,
    const float* __restrict__ fc11_b, const float* __restrict__ fc12_b,
    const short* __restrict__ encWT,
    const short* __restrict__ fc11WT, const short* __restrict__ fc12WT,
    const short* __restrict__ ef16, const short* __restrict__ efU16,
    float* __restrict__ pooled,
    short* __restrict__ zbuf, float* __restrict__ vae_part)
{
    __shared__ int   featsL[320];
    __shared__ int   spi[16], sci[16];
    __shared__ __align__(16) short hlds[2048];
    __shared__ float sdots[4][16][3];
    __shared__ float red[256];

    const int t    = threadIdx.x;
    const int w    = t >> 6;
    const int lane = t & 63;
    const int g    = lane >> 4;
    const int q    = lane & 15;
    const size_t SEC = (size_t)BATCH * DIM;

    if (blockIdx.x < 1536) {
        // ======================= POOL BLOCKS =======================
        const int pb  = blockIdx.x;
        const int br  = pb >> 9;                 // 0,1,2
        const int i   = (pb & 511) * 8 + (t >> 5);
        const int j32 = t & 31;
        if (br == 0) {
            pool_online<LU>(user_idx, user_feat, emb_user,
                            (const unsigned short*)efU16, pop_u, int_u,
                            pooled + 0 * SEC, pooled + 1 * SEC, i, j32);
        } else if (br == 1) {
            pool_online<LI>(pos_idx, pos_feat, emb_item,
                            (const unsigned short*)ef16, pop_i, int_i,
                            pooled + 2 * SEC, pooled + 3 * SEC, i, j32);
        } else {
            pool_online<LI>(neg_idx, neg_feat, emb_item,
                            (const unsigned short*)ef16, pop_i, int_i,
                            pooled + 4 * SEC, pooled + 5 * SEC, i, j32);
        }
        return;
    }

    // ======================= ENC/Z BLOCKS =======================
    const int sg = blockIdx.x - 1536;
    const int i0 = sg * 16;

    if (t < 16)      spi[t] = pos_idx[i0 + t];
    else if (t < 32) sci[t - 16] = comp_idx[i0 + t - 16];
    if (t < 256) featsL[t] = pos_feat[i0 * LI + t];
    if (t < 64)  featsL[256 + t] = pos_feat[i0 * LI + 256 + t];
    __syncthreads();

    const int j0 = w * 32 + q;
    const int j1 = j0 + 16;
    const short* bbase0 = encWT + (size_t)j0 * 2560 + g * 8;
    const short* bbase1 = encWT + (size_t)j1 * 2560 + g * 8;

    f32x4 acc0 = {0.f, 0.f, 0.f, 0.f};
    f32x4 acc1 = {0.f, 0.f, 0.f, 0.f};
    for (int l = 0; l < LI; ++l) {
        const int f = featsL[q * LI + l];
        const short* arow = ef16 + (size_t)f * DIM + g * 8;
#pragma unroll
        for (int dt = 0; dt < 4; ++dt) {
            const int koff = l * 128 + dt * 32;
            s16x8 a  = *(const s16x8*)(arow + dt * 32);
            s16x8 b0 = *(const s16x8*)(bbase0 + koff);
            s16x8 b1 = *(const s16x8*)(bbase1 + koff);
            acc0 = __builtin_amdgcn_mfma_f32_16x16x32_bf16(a, b0, acc0, 0, 0, 0);
            acc1 = __builtin_amdgcn_mfma_f32_16x16x32_bf16(a, b1, acc1, 0, 0, 0);
        }
    }

    {
        float eb0 = enc_b[j0], eb1 = enc_b[j1];
#pragma unroll
        for (int r = 0; r < 4; ++r) {
            int s = g * 4 + r;
            float h0 = acc0[r] + eb0; h0 = h0 > 0.f ? h0 : 0.f;
            float h1 = acc1[r] + eb1; h1 = h1 > 0.f ? h1 : 0.f;
            int swz = (s & 7) << 3;
            hlds[(s * 128 + j0) ^ swz] = f2bf(h0);
            hlds[(s * 128 + j1) ^ swz] = f2bf(h1);
        }
    }
    __syncthreads();

    const short* fb0_11 = fc11WT + (size_t)j0 * DIM + g * 8;
    const short* fb1_11 = fc11WT + (size_t)j1 * DIM + g * 8;
    const short* fb0_12 = fc12WT + (size_t)j0 * DIM + g * 8;
    const short* fb1_12 = fc12WT + (size_t)j1 * DIM + g * 8;

    f32x4 mu0 = {0.f,0.f,0.f,0.f}, mu1 = {0.f,0.f,0.f,0.f};
    f32x4 lv0 = {0.f,0.f,0.f,0.f}, lv1 = {0.f,0.f,0.f,0.f};
#pragma unroll
    for (int kt = 0; kt < 4; ++kt) {
        int sidx = (q * 128 + kt * 32 + g * 8) ^ ((q & 7) << 3);
        s16x8 a = *(const s16x8*)&hlds[sidx];
        s16x8 w11a = *(const s16x8*)(fb0_11 + kt * 32);
        s16x8 w11b = *(const s16x8*)(fb1_11 + kt * 32);
        s16x8 w12a = *(const s16x8*)(fb0_12 + kt * 32);
        s16x8 w12b = *(const s16x8*)(fb1_12 + kt * 32);
        mu0 = __builtin_amdgcn_mfma_f32_16x16x32_bf16(a, w11a, mu0, 0, 0, 0);
        mu1 = __builtin_amdgcn_mfma_f32_16x16x32_bf16(a, w11b, mu1, 0, 0, 0);
        lv0 = __builtin_amdgcn_mfma_f32_16x16x32_bf16(a, w12a, lv0, 0, 0, 0);
        lv1 = __builtin_amdgcn_mfma_f32_16x16x32_bf16(a, w12b, lv1, 0, 0, 0);
    }

    float b11_0 = fc11_b[j0], b11_1 = fc11_b[j1];
    float b12_0 = fc12_b[j0], b12_1 = fc12_b[j1];

    float kacc = 0.f;
#pragma unroll
    for (int r = 0; r < 4; ++r) {
        const int s = g * 4 + r;
        const int i = i0 + s;
        float m0 = mu0[r] + b11_0, m1 = mu1[r] + b11_1;
        float v0 = lv0[r] + b12_0, v1 = lv1[r] + b12_1;
        float e0 = eps[(size_t)i * DIM + j0];
        float e1 = eps[(size_t)i * DIM + j1];
        float z0 = e0 * expf(0.5f * v0) + m0;
        float z1 = e1 * expf(0.5f * v1) + m1;
        zbuf[(size_t)i * DIM + j0] = f2bf(z0);
        zbuf[(size_t)i * DIM + j1] = f2bf(z1);
        kacc += (1.f + v0 - m0 * m0 - expf(v0)) + (1.f + v1 - m1 * m1 - expf(v1));

        const size_t pb2 = (size_t)spi[s] * DIM;
        const size_t cb2 = (size_t)sci[s] * DIM;
        float pe0 = emb_item[pb2 + j0], pe1 = emb_item[pb2 + j1];
        float ce0 = emb_item[cb2 + j0], ce1 = emb_item[cb2 + j1];
        float zp = z0 * pe0 + z1 * pe1;
        float zc = z0 * ce0 + z1 * ce1;
        float d0 = z0 - pe0, d1 = z1 - pe1;
        float zq = d0 * d0 + d1 * d1;
        for (int mm = 8; mm >= 1; mm >>= 1) {
            zp += __shfl_xor(zp, mm, 64);
            zc += __shfl_xor(zc, mm, 64);
            zq += __shfl_xor(zq, mm, 64);
        }
        if (q == 0) {
            sdots[w][s][0] = zp;
            sdots[w][s][1] = zc;
            sdots[w][s][2] = zq;
        }
    }

    red[t] = -0.5f * kacc;
    __syncthreads();
    if (t < 16) {
        float zp = 0.f, zc = 0.f, zq = 0.f;
        for (int ww = 0; ww < 4; ++ww) {
            zp += sdots[ww][t][0];
            zc += sdots[ww][t][1];
            zq += sdots[ww][t][2];
        }
        float x = zp - zc;
        float ls = (x >= 0.f) ? -log1pf(expf(-x)) : (x - log1pf(expf(x)));
        red[t] += -ls + zq;
    }
    __syncthreads();
    for (int off = 128; off > 0; off >>= 1) {
        if (t < off) red[t] += red[t + off];
        __syncthreads();
    }
    if (t == 0) vae_part[sg] = red[0];
}

// ---------------------------------------------------------------------------
// k_C: 2304 blocks x 256 threads.
//   blocks [0,2048)    : decoder col-split x8 -> mse partials
//   blocks [2048,2304) : triplet losses via MFMA (reads global pooled)
// ---------------------------------------------------------------------------
__global__ __launch_bounds__(256) void k_C(
    const float* __restrict__ pooled,
    const short* __restrict__ wpopT, const short* __restrict__ wintT,
    const int* __restrict__ pos_feat,
    const float* __restrict__ ef_item, const float* __restrict__ dec_b,
    const short* __restrict__ decWT, const short* __restrict__ zbuf,
    float* __restrict__ out_hot, float* __restrict__ out_cold,
    float* __restrict__ dec_part)
{
    __shared__ int   featsL[320];
    __shared__ float red[256];
    __shared__ float sArr[4][16];

    const int t    = threadIdx.x;
    const int w    = t >> 6;
    const int lane = t & 63;
    const int g    = lane >> 4;
    const int q    = lane & 15;

    if (blockIdx.x >= 2048) {
        // =================== TRIPLET LOSS BLOCKS ===================
        const int i0 = (blockIdx.x - 2048) * 16;
        const int h     = w >> 1;
        const int other = (w & 1) + 1;
        const float* pu = pooled + (size_t)(0 * 2 + h) * BATCH * DIM;
        const float* po = pooled + (size_t)(other * 2 + h) * BATCH * DIM;
        const short* wT = h ? wintT : wpopT;

        s16x8 afr[4];
#pragma unroll
        for (int kt = 0; kt < 4; ++kt) {
            const size_t off = (size_t)(i0 + q) * DIM + kt * 32 + g * 8;
            f32x4 ua = *(const f32x4*)(pu + off);
            f32x4 ub = *(const f32x4*)(pu + off + 4);
            f32x4 oa = *(const f32x4*)(po + off);
            f32x4 ob = *(const f32x4*)(po + off + 4);
            s16x8 v;
            v[0] = f2bf(ua[0] - oa[0]); v[1] = f2bf(ua[1] - oa[1]);
            v[2] = f2bf(ua[2] - oa[2]); v[3] = f2bf(ua[3] - oa[3]);
            v[4] = f2bf(ub[0] - ob[0]); v[5] = f2bf(ub[1] - ob[1]);
            v[6] = f2bf(ub[2] - ob[2]); v[7] = f2bf(ub[3] - ob[3]);
            afr[kt] = v;
        }

        float sq0 = 0.f, sq1 = 0.f, sq2 = 0.f, sq3 = 0.f;
        for (int fr = 0; fr < 8; ++fr) {
            const short* bb = wT + (size_t)(fr * 16 + q) * DIM + g * 8;
            f32x4 acc = {0.f, 0.f, 0.f, 0.f};
#pragma unroll
            for (int kt = 0; kt < 4; ++kt) {
                s16x8 bfr = *(const s16x8*)(bb + kt * 32);
                acc = __builtin_amdgcn_mfma_f32_16x16x32_bf16(afr[kt], bfr, acc, 0, 0, 0);
            }
            sq0 += acc[0] * acc[0]; sq1 += acc[1] * acc[1];
            sq2 += acc[2] * acc[2]; sq3 += acc[3] * acc[3];
        }
        for (int m = 8; m >= 1; m >>= 1) {
            sq0 += __shfl_xor(sq0, m, 64);
            sq1 += __shfl_xor(sq1, m, 64);
            sq2 += __shfl_xor(sq2, m, 64);
            sq3 += __shfl_xor(sq3, m, 64);
        }
        if (q == 0) {
            sArr[w][g * 4 + 0] = sq0;
            sArr[w][g * 4 + 1] = sq1;
            sArr[w][g * 4 + 2] = sq2;
            sArr[w][g * 4 + 3] = sq3;
        }
        __syncthreads();
        if (t < 16) {
            float v = sArr[0][t] - sArr[1][t] + 1.0f;
            out_hot[i0 + t] = v > 0.f ? v : 0.f;
        } else if (t < 32) {
            int s = t - 16;
            float v = sArr[2][s] - sArr[3][s] + 1.0f;
            out_cold[i0 + s] = v > 0.f ? v : 0.f;
        }
        return;
    }

    // ====================== DECODER BLOCKS ======================
    const int db     = blockIdx.x;           // [0,2048)
    const int cchunk = db >> 8;
    const int sb     = db & 255;
    const int i0     = sb * 16;

    if (t < 256) featsL[t] = pos_feat[i0 * LI + t];
    if (t < 64)  featsL[256 + t] = pos_feat[i0 * LI + 256 + t];
    __syncthreads();

    s16x8 za[4];
#pragma unroll
    for (int kt = 0; kt < 4; ++kt)
        za[kt] = *(const s16x8*)(zbuf + (size_t)(i0 + q) * DIM + kt * 32 + g * 8);

    const int cw = cchunk * 320 + w * 80;

    s16x8 bb[5][4];
    float xs[5][4];
    float bias[5];
#pragma unroll
    for (int fp = 0; fp < 5; ++fp) {
        const int c = cw + fp * 16 + q;
        const short* bp = decWT + (size_t)c * DIM + g * 8;
#pragma unroll
        for (int kt = 0; kt < 4; ++kt)
            bb[fp][kt] = *(const s16x8*)(bp + kt * 32);
        const int l = c >> 7, dcol = c & 127;
#pragma unroll
        for (int r = 0; r < 4; ++r)
            xs[fp][r] = ef_item[(size_t)featsL[(g * 4 + r) * LI + l] * DIM + dcol];
        bias[fp] = dec_b[c];
    }

    float macc = 0.f;
#pragma unroll
    for (int fp = 0; fp < 5; ++fp) {
        f32x4 acc = {0.f, 0.f, 0.f, 0.f};
#pragma unroll
        for (int kt = 0; kt < 4; ++kt)
            acc = __builtin_amdgcn_mfma_f32_16x16x32_bf16(za[kt], bb[fp][kt], acc, 0, 0, 0);
#pragma unroll
        for (int r = 0; r < 4; ++r) {
            float dd = acc[r] + bias[fp] - xs[fp][r];
            macc += dd * dd;
        }
    }

    red[t] = macc;
    __syncthreads();
    for (int off = 128; off > 0; off >>= 1) {
        if (t < off) red[t] += red[t + off];
        __syncthreads();
    }
    if (t == 0) dec_part[db] = red[0];
}

// ---------------------------------------------------------------------------
// k_E: scalar = sum(vae_part) + 0.05 * sum(dec_part).
// ---------------------------------------------------------------------------
__global__ __launch_bounds__(256) void k_E(
    const float* __restrict__ vae_part, const float* __restrict__ dec_part,
    float* __restrict__ out_scalar)
{
    __shared__ float red[256];
    const int t = threadIdx.x;
    float b3 = 0.f;
    for (int qq = t; qq < 2048; qq += 256) b3 += dec_part[qq];
    red[t] = vae_part[t] + 0.05f * b3;   // mse / LI  (LI = 20)
    __syncthreads();
    for (int off = 128; off > 0; off >>= 1) {
        if (t < off) red[t] += red[t + off];
        __syncthreads();
    }
    if (t == 0) out_scalar[0] = red[0];
}

// ---------------------------------------------------------------------------
extern "C" void kernel_launch(void* const* d_in, const int* in_sizes, int n_in,
                              void* d_out, int out_size, void* d_ws, size_t ws_size,
                              hipStream_t stream) {
    const int*   user_idx  = (const int*)d_in[0];
    const int*   user_feat = (const int*)d_in[1];
    const int*   pos_idx   = (const int*)d_in[2];
    const int*   pos_feat  = (const int*)d_in[3];
    const int*   neg_idx   = (const int*)d_in[4];
    const int*   neg_feat  = (const int*)d_in[5];
    const int*   comp_idx  = (const int*)d_in[6];
    const float* eps       = (const float*)d_in[7];
    const float* emb_user  = (const float*)d_in[8];
    const float* emb_item  = (const float*)d_in[9];
    const float* ef_user   = (const float*)d_in[10];
    const float* ef_item   = (const float*)d_in[11];
    const float* pop_u     = (const float*)d_in[12];
    const float* int_u     = (const float*)d_in[13];
    const float* pop_i     = (const float*)d_in[14];
    const float* int_i     = (const float*)d_in[15];
    const float* W_pop     = (const float*)d_in[16];
    const float* W_int     = (const float*)d_in[18];
    const float* enc_W     = (const float*)d_in[20];
    const float* enc_b     = (const float*)d_in[21];
    const float* dec_W     = (const float*)d_in[22];
    const float* dec_b     = (const float*)d_in[23];
    const float* fc11_W    = (const float*)d_in[24];
    const float* fc11_b    = (const float*)d_in[25];
    const float* fc12_W    = (const float*)d_in[26];
    const float* fc12_b    = (const float*)d_in[27];

    float* out = (float*)d_out;
    char*  ws  = (char*)d_ws;

    short* encWT    = (short*)(ws);                    //   655,360 B
    short* decWT    = (short*)(ws + 655360);           //   655,360
    short* fc11WT   = (short*)(ws + 1310720);          //    32,768
    short* fc12WT   = (short*)(ws + 1343488);          //    32,768
    short* wpopT    = (short*)(ws + 1376256);          //    32,768
    short* wintT    = (short*)(ws + 1409024);          //    32,768
    short* ef16     = (short*)(ws + 1441792);          // 1,280,000
    short* efU16    = (short*)(ws + 2721792);          //   512,000
    short* zbuf     = (short*)(ws + 3233792);          // 1,048,576
    float* pooled   = (float*)(ws + 4282368);          // 12,582,912
    float* vae_part = (float*)(ws + 16865280);         //     1,024
    float* dec_part = (float*)(ws + 16866304);         //     8,192

    k_prep<<<dim3(1579), dim3(256), 0, stream>>>(
        enc_W, dec_W, fc11_W, fc12_W, W_pop, W_int, ef_item, ef_user,
        encWT, decWT, fc11WT, fc12WT, wpopT, wintT, ef16, efU16);

    k_AB<<<dim3(1792), dim3(256), 0, stream>>>(
        user_idx, user_feat, pos_idx, pos_feat, neg_idx, neg_feat, comp_idx,
        emb_user, emb_item,
        pop_u, int_u, pop_i, int_i,
        eps, enc_b, fc11_b, fc12_b,
        encWT, fc11WT, fc12WT, ef16, efU16,
        pooled, zbuf, vae_part);

    k_C<<<dim3(2304), dim3(256), 0, stream>>>(
        pooled, wpopT, wintT, pos_feat, ef_item, dec_b, decWT, zbuf,
        out, out + BATCH, dec_part);

    k_E<<<dim3(1), dim3(256), 0, stream>>>(vae_part, dec_part, out + 2 * BATCH);
}